// Round 6
// baseline (593.465 us; speedup 1.0000x reference)
//
#include <hip/hip_runtime.h>
#include <hip/hip_bf16.h>

#define NUM_TASKS 50
#define NUM_EXPERTS 8
#define WIDTH 1024
#define FEAT 512
#define HEAD_DIM 256
#define BATCH 4096
#define XCOLS (FEAT + NUM_TASKS)   // 562
#define MAXGRP 576                 // >= 512 + 50 (ceil-groups of 8)
#define SMAX 561                   // max real groups (512 + 49)

typedef unsigned short ushort_t;
typedef short bf16x8 __attribute__((ext_vector_type(8)));
typedef float f32x4 __attribute__((ext_vector_type(4)));

// fp32 -> bf16 (RNE) raw bits
__device__ __forceinline__ ushort_t f2b(float f) {
    unsigned u = __float_as_uint(f);
    unsigned r = (u + 0x7fffu + ((u >> 16) & 1u)) >> 16;
    return (ushort_t)r;
}
__device__ __forceinline__ float b2f_lo(unsigned u) { return __uint_as_float(u << 16); }
__device__ __forceinline__ float b2f_hi(unsigned u) { return __uint_as_float(u & 0xffff0000u); }

__device__ __forceinline__ void async16(const ushort_t* g, ushort_t* l) {
    __builtin_amdgcn_global_load_lds(
        (const __attribute__((address_space(1))) unsigned int*)g,
        (__attribute__((address_space(3))) unsigned int*)l,
        16, 0, 0);
}

// ---------------------------------------------------------------------------
// prep: task id + emb
// ---------------------------------------------------------------------------
__global__ void prep_kernel(const float* __restrict__ x,
                            const float* __restrict__ W_emb,
                            const float* __restrict__ b_emb,
                            float* __restrict__ emb,
                            int* __restrict__ tids) {
    int b = blockIdx.x;
    int lane = threadIdx.x;  // 64
    float v = 0.f;
    if (lane < NUM_TASKS) v = x[(size_t)b * XCOLS + FEAT + lane];
    unsigned long long mask = __ballot(v > 0.5f);
    int tid = __ffsll(mask) - 1;
    if (tid < 0) tid = 0;
    if (tid > NUM_TASKS - 1) tid = NUM_TASKS - 1;
    if (lane == 0) tids[b] = tid;
    if (lane < NUM_EXPERTS)
        emb[(size_t)b * NUM_EXPERTS + lane] =
            W_emb[tid * NUM_EXPERTS + lane] + b_emb[lane];
}

// ---------------------------------------------------------------------------
// counting sort by task + group table + XCD-pinned schedule.
// sched[x][s]: group ids for XCD x (task t -> XCD t&7), -1 = empty slot.
// All groups of one task land on ONE XCD -> W_head[t] stays in that L2.
// ---------------------------------------------------------------------------
__global__ void sort_kernel(const int* __restrict__ tids,
                            int* __restrict__ pos,      // [BATCH] b -> sorted slot
                            int* __restrict__ row_map,  // [BATCH] sorted slot -> b
                            int* __restrict__ grp,      // [MAXGRP][3] task,start,cnt
                            int* __restrict__ sched) {  // [8][SMAX]
    __shared__ int cnt[NUM_TASKS];
    __shared__ int start[NUM_TASKS];
    __shared__ int rank[NUM_TASKS];
    int t = threadIdx.x;
    if (t < NUM_TASKS) { cnt[t] = 0; rank[t] = 0; }
    for (int i = t; i < 8 * SMAX; i += 256) sched[i] = -1;
    __syncthreads();
    for (int b = t; b < BATCH; b += 256) atomicAdd(&cnt[tids[b]], 1);
    __syncthreads();
    if (t == 0) {
        int acc = 0, ng = 0;
        int xcnt[8] = {0, 0, 0, 0, 0, 0, 0, 0};
        for (int k = 0; k < NUM_TASKS; ++k) {
            start[k] = acc;
            int c = cnt[k];
            int x = k & 7;
            for (int o = 0; o < c; o += 8) {
                int rem = c - o;
                grp[3 * ng + 0] = k;
                grp[3 * ng + 1] = acc + o;
                grp[3 * ng + 2] = rem < 8 ? rem : 8;
                sched[x * SMAX + xcnt[x]] = ng;
                ++xcnt[x];
                ++ng;
            }
            acc += c;
        }
    }
    __syncthreads();
    for (int b = t; b < BATCH; b += 256) {
        int tk = tids[b];
        int p = start[tk] + atomicAdd(&rank[tk], 1);
        pos[b] = p;
        row_map[p] = b;
    }
}

// ---------------------------------------------------------------------------
// conversions
// ---------------------------------------------------------------------------
__global__ void conv_x_kernel(const float* __restrict__ x, ushort_t* __restrict__ xb) {
    int b = blockIdx.x, t = threadIdx.x;
    #pragma unroll
    for (int q = 0; q < 2; ++q) {
        int i = t + 256 * q;
        xb[(size_t)b * FEAT + i] = f2b(x[(size_t)b * XCOLS + i]);
    }
}

__global__ void conv_wt_kernel(const float* __restrict__ W, ushort_t* __restrict__ Wt, int K) {
    int k0 = blockIdx.x * 32, n0 = blockIdx.y * 32, e = blockIdx.z;
    __shared__ float tile[32][33];
    const float* Wb = W + (size_t)e * K * WIDTH;
    ushort_t* Wtb = Wt + (size_t)e * WIDTH * K;
    int t = threadIdx.x;
    #pragma unroll
    for (int q = 0; q < 4; ++q) {
        int i = t + 256 * q; int ki = i >> 5, ni = i & 31;
        tile[ki][ni] = Wb[(size_t)(k0 + ki) * WIDTH + n0 + ni];
    }
    __syncthreads();
    #pragma unroll
    for (int q = 0; q < 4; ++q) {
        int i = t + 256 * q; int ni = i >> 5, ki = i & 31;
        Wtb[(size_t)(n0 + ni) * K + k0 + ki] = f2b(tile[ki][ni]);
    }
}

// ---------------------------------------------------------------------------
// MFMA expert-batched GEMM (unchanged - passing)
// ---------------------------------------------------------------------------
template <bool RELU>
__global__ __launch_bounds__(256) void mfma_gemm(
    const ushort_t* __restrict__ A, int lda, int aoff,
    const ushort_t* __restrict__ Bt,
    const float* __restrict__ bias,
    ushort_t* __restrict__ C, int K)
{
    const int m0 = blockIdx.x * 128;
    const int n0 = blockIdx.y * 128;
    const int e  = blockIdx.z;
    const int t  = threadIdx.x;
    const int l  = t & 63;

    __shared__ __align__(16) ushort_t As[128 * 32];
    __shared__ __align__(16) ushort_t Bs[128 * 32];

    const ushort_t* __restrict__ Ab = A + (size_t)e * aoff + (size_t)m0 * lda;
    const ushort_t* __restrict__ Bb = Bt + ((size_t)e * WIDTH + n0) * K;

    const int srow = t >> 2;
    const int scol = (t & 3) * 8;

    const int w  = t >> 6;
    const int wm = (w >> 1) * 64;
    const int wn = (w & 1) * 64;
    const int lm = l & 15;
    const int lk = (l >> 4) * 8;

    f32x4 acc[4][4];
    #pragma unroll
    for (int i = 0; i < 4; ++i)
        #pragma unroll
        for (int j = 0; j < 4; ++j) acc[i][j] = {0.f, 0.f, 0.f, 0.f};

    for (int kt = 0; kt < K; kt += 32) {
        __syncthreads();
        async16(Ab + (size_t)srow * lda + kt + scol,        &As[t * 8]);
        async16(Ab + (size_t)(srow + 64) * lda + kt + scol, &As[2048 + t * 8]);
        async16(Bb + (size_t)srow * K + kt + scol,          &Bs[t * 8]);
        async16(Bb + (size_t)(srow + 64) * K + kt + scol,   &Bs[2048 + t * 8]);
        __syncthreads();

        bf16x8 af[4], bfr[4];
        #pragma unroll
        for (int mi = 0; mi < 4; ++mi)
            af[mi] = *reinterpret_cast<const bf16x8*>(&As[(wm + mi * 16 + lm) * 32 + lk]);
        #pragma unroll
        for (int ni = 0; ni < 4; ++ni)
            bfr[ni] = *reinterpret_cast<const bf16x8*>(&Bs[(wn + ni * 16 + lm) * 32 + lk]);
        #pragma unroll
        for (int mi = 0; mi < 4; ++mi)
            #pragma unroll
            for (int ni = 0; ni < 4; ++ni)
                acc[mi][ni] = __builtin_amdgcn_mfma_f32_16x16x32_bf16(
                    af[mi], bfr[ni], acc[mi][ni], 0, 0, 0);
    }

    const int rbase = (l >> 4) * 4;
    #pragma unroll
    for (int mi = 0; mi < 4; ++mi) {
        #pragma unroll
        for (int ni = 0; ni < 4; ++ni) {
            int col = n0 + wn + ni * 16 + lm;
            float bv = bias[e * WIDTH + col];
            #pragma unroll
            for (int r = 0; r < 4; ++r) {
                int row = m0 + wm + mi * 16 + rbase + r;
                float v = acc[mi][ni][r] + bv;
                if (RELU) v = fmaxf(v, 0.f);
                C[(size_t)row * (NUM_EXPERTS * WIDTH) + e * WIDTH + col] = f2b(v);
            }
        }
    }
}

// ---------------------------------------------------------------------------
// Wave-per-row register Gram-Schmidt (unchanged - passing)
// ---------------------------------------------------------------------------
__device__ __forceinline__ float wave_sum(float x) {
    #pragma unroll
    for (int off = 1; off < 64; off <<= 1) x += __shfl_xor(x, off, 64);
    return x;
}
__device__ __forceinline__ void u2f8(uint4 a, float* f) {
    f[0] = b2f_lo(a.x); f[1] = b2f_hi(a.x);
    f[2] = b2f_lo(a.y); f[3] = b2f_hi(a.y);
    f[4] = b2f_lo(a.z); f[5] = b2f_hi(a.z);
    f[6] = b2f_lo(a.w); f[7] = b2f_hi(a.w);
}

__global__ __launch_bounds__(256, 1) void gs_wave_kernel(
    const ushort_t* __restrict__ eo,   // [CHUNK][8][1024] bf16
    const float* __restrict__ emb,     // [CHUNK][8]
    const int* __restrict__ pos,       // [CHUNK] global sorted slot
    float* __restrict__ featsS)        // [BATCH][1024] fp32 (sorted)
{
    const int w = threadIdx.x >> 6;
    const int l = threadIdx.x & 63;
    const int r = blockIdx.x * 4 + w;

    float v[NUM_EXPERTS][16];
    const ushort_t* row = eo + (size_t)r * (NUM_EXPERTS * WIDTH);
    #pragma unroll
    for (int e = 0; e < NUM_EXPERTS; ++e) {
        const uint4* p = reinterpret_cast<const uint4*>(row + e * WIDTH + l * 16);
        u2f8(p[0], &v[e][0]);
        u2f8(p[1], &v[e][8]);
    }

    {
        float s = 0.f;
        #pragma unroll
        for (int j = 0; j < 16; ++j) s += v[0][j] * v[0][j];
        s = wave_sum(s);
        float inv = 1.f / sqrtf(s);
        #pragma unroll
        for (int j = 0; j < 16; ++j) v[0][j] *= inv;
    }

    #pragma unroll
    for (int i = 1; i < NUM_EXPERTS; ++i) {
        float c[NUM_EXPERTS];
        #pragma unroll
        for (int jj = 0; jj < i; ++jj) {
            float p = 0.f;
            #pragma unroll
            for (int j = 0; j < 16; ++j) p += v[i][j] * v[jj][j];
            c[jj] = wave_sum(p);
        }
        float s = 0.f;
        #pragma unroll
        for (int j = 0; j < 16; ++j) {
            float wv = v[i][j];
            #pragma unroll
            for (int jj = 0; jj < i; ++jj) wv -= c[jj] * v[jj][j];
            v[i][j] = wv;
            s += wv * wv;
        }
        s = wave_sum(s);
        float inv = 1.f / sqrtf(s);
        #pragma unroll
        for (int j = 0; j < 16; ++j) v[i][j] *= inv;
    }

    float er[NUM_EXPERTS];
    #pragma unroll
    for (int e = 0; e < NUM_EXPERTS; ++e) er[e] = emb[(size_t)r * NUM_EXPERTS + e];
    float f[16];
    #pragma unroll
    for (int j = 0; j < 16; ++j) {
        float s = 0.f;
        #pragma unroll
        for (int e = 0; e < NUM_EXPERTS; ++e) s += v[e][j] * er[e];
        f[j] = fmaxf(s, 0.f);
    }
    int p = pos[r];
    float4* dst = reinterpret_cast<float4*>(featsS + (size_t)p * WIDTH + l * 16);
    #pragma unroll
    for (int q = 0; q < 4; ++q) dst[q] = *reinterpret_cast<float4*>(&f[4 * q]);
}

// ---------------------------------------------------------------------------
// XCD-scheduled task-grouped head. grid = 8 * SMAX flattened; xcd = blk & 7
// (dispatch round-robins blocks across XCDs -> all groups of a task share L2).
// fs[8][1024] staged dense (ds_write_b128, conflict-free); inner loop reads
// fs[r][k..k+3] via same-address broadcast (free) + coalesced W_head load.
// ---------------------------------------------------------------------------
__global__ __launch_bounds__(256) void head_kernel(
    const float* __restrict__ featsS,   // [BATCH][1024] sorted
    const int* __restrict__ row_map,    // sorted slot -> b
    const int* __restrict__ grp,
    const int* __restrict__ sched,      // [8][SMAX]
    const float* __restrict__ W_head,   // [50][1024][256]
    const float* __restrict__ b_head,   // [50][256]
    float* __restrict__ out)            // [BATCH][256]
{
    const int x = blockIdx.x & 7;
    const int s = blockIdx.x >> 3;
    const int g = sched[x * SMAX + s];
    if (g < 0) return;
    const int t   = grp[3 * g + 0];
    const int s0  = grp[3 * g + 1];
    const int cnt = grp[3 * g + 2];
    const int d = threadIdx.x;

    __shared__ __align__(16) float fs[8][WIDTH];  // 32 KB
    #pragma unroll
    for (int r = 0; r < 8; ++r) {
        float4 v = {0.f, 0.f, 0.f, 0.f};
        if (r < cnt)
            v = *reinterpret_cast<const float4*>(featsS + (size_t)(s0 + r) * WIDTH + d * 4);
        *reinterpret_cast<float4*>(&fs[r][d * 4]) = v;
    }
    __syncthreads();

    const float* __restrict__ Wh = W_head + (size_t)t * WIDTH * HEAD_DIM + d;
    float acc[8] = {};
    for (int k = 0; k < WIDTH; k += 4) {
        float w0 = Wh[(size_t)(k + 0) * HEAD_DIM];
        float w1 = Wh[(size_t)(k + 1) * HEAD_DIM];
        float w2 = Wh[(size_t)(k + 2) * HEAD_DIM];
        float w3 = Wh[(size_t)(k + 3) * HEAD_DIM];
        #pragma unroll
        for (int r = 0; r < 8; ++r) {
            float4 f = *reinterpret_cast<const float4*>(&fs[r][k]);  // broadcast
            acc[r] += f.x * w0 + f.y * w1 + f.z * w2 + f.w * w3;
        }
    }
    float bb = b_head[t * HEAD_DIM + d];
    for (int r = 0; r < cnt; ++r)
        out[(size_t)row_map[s0 + r] * HEAD_DIM + d] = acc[r] + bb;
}

// ---------------------------------------------------------------------------
extern "C" void kernel_launch(void* const* d_in, const int* in_sizes, int n_in,
                              void* d_out, int out_size, void* d_ws, size_t ws_size,
                              hipStream_t stream) {
    const float* x      = (const float*)d_in[0];
    const float* W_emb  = (const float*)d_in[1];
    const float* b_emb  = (const float*)d_in[2];
    const float* W0     = (const float*)d_in[3];
    const float* b0     = (const float*)d_in[4];
    const float* W1     = (const float*)d_in[5];
    const float* b1     = (const float*)d_in[6];
    const float* Wout   = (const float*)d_in[7];
    const float* bout   = (const float*)d_in[8];
    const float* W_head = (const float*)d_in[9];
    const float* b_head = (const float*)d_in[10];
    float* out = (float*)d_out;

    char* ws = (char*)d_ws;
    size_t off = 0;
    auto take = [&](size_t bytes) { char* p = ws + off; off += (bytes + 255) & ~(size_t)255; return p; };
    float*    emb     = (float*)   take((size_t)BATCH * NUM_EXPERTS * sizeof(float));
    int*      tids    = (int*)     take((size_t)BATCH * sizeof(int));
    int*      pos     = (int*)     take((size_t)BATCH * sizeof(int));
    int*      row_map = (int*)     take((size_t)BATCH * sizeof(int));
    int*      grp     = (int*)     take((size_t)MAXGRP * 3 * sizeof(int));
    int*      sched   = (int*)     take((size_t)8 * SMAX * sizeof(int));
    ushort_t* xb      = (ushort_t*)take((size_t)BATCH * FEAT * 2);
    ushort_t* W0t     = (ushort_t*)take((size_t)NUM_EXPERTS * WIDTH * FEAT * 2);
    ushort_t* W1t     = (ushort_t*)take((size_t)NUM_EXPERTS * WIDTH * WIDTH * 2);
    ushort_t* Woutt   = (ushort_t*)take((size_t)NUM_EXPERTS * WIDTH * WIDTH * 2);
    float*    featsS  = (float*)   take((size_t)BATCH * WIDTH * sizeof(float));
    char* bufbase = ws + off;

    const size_t ROWB = (size_t)NUM_EXPERTS * WIDTH * 2;  // 16 KB/row
    size_t avail = ws_size > off ? ws_size - off : 0;
    int CHUNK;
    if      (avail >= 2 * (size_t)4096 * ROWB) CHUNK = 4096;
    else if (avail >= 2 * (size_t)2048 * ROWB) CHUNK = 2048;
    else if (avail >= 2 * (size_t)1024 * ROWB) CHUNK = 1024;
    else                                       CHUNK = 512;

    ushort_t* bufA = (ushort_t*)bufbase;
    ushort_t* bufB = (ushort_t*)(bufbase + (size_t)CHUNK * ROWB);

    prep_kernel<<<BATCH, 64, 0, stream>>>(x, W_emb, b_emb, emb, tids);
    sort_kernel<<<1, 256, 0, stream>>>(tids, pos, row_map, grp, sched);
    conv_x_kernel<<<BATCH, 256, 0, stream>>>(x, xb);
    conv_wt_kernel<<<dim3(FEAT / 32, WIDTH / 32, NUM_EXPERTS), 256, 0, stream>>>(W0, W0t, FEAT);
    conv_wt_kernel<<<dim3(WIDTH / 32, WIDTH / 32, NUM_EXPERTS), 256, 0, stream>>>(W1, W1t, WIDTH);
    conv_wt_kernel<<<dim3(WIDTH / 32, WIDTH / 32, NUM_EXPERTS), 256, 0, stream>>>(Wout, Woutt, WIDTH);

    dim3 grid(CHUNK / 128, WIDTH / 128, NUM_EXPERTS);
    for (int r0 = 0; r0 < BATCH; r0 += CHUNK) {
        const ushort_t* xc = xb + (size_t)r0 * FEAT;
        mfma_gemm<true ><<<grid, 256, 0, stream>>>(xc, FEAT, 0, W0t, b0, bufA, FEAT);
        mfma_gemm<true ><<<grid, 256, 0, stream>>>(bufA, NUM_EXPERTS * WIDTH, WIDTH, W1t, b1, bufB, WIDTH);
        mfma_gemm<false><<<grid, 256, 0, stream>>>(bufB, NUM_EXPERTS * WIDTH, WIDTH, Woutt, bout, bufA, WIDTH);
        gs_wave_kernel<<<CHUNK / 4, 256, 0, stream>>>(bufA, emb + (size_t)r0 * NUM_EXPERTS,
                                                      pos + r0, featsS);
    }
    head_kernel<<<8 * SMAX, 256, 0, stream>>>(featsS, row_map, grp, sched, W_head, b_head, out);
}